// Round 8
// baseline (1088.489 us; speedup 1.0000x reference)
//
#include <hip/hip_runtime.h>
#include <hip/hip_bf16.h>

#define N_ 100000
#define E_ 3200000
#define DIM 300
#define HID 16
#define NGRAPH 5
#define NB 196         // buckets/graph, 512 nodes each (196*512 >= 100000)
#define BSH 9
#define BNODES 512
#define CAP 20480      // mean 16384 edges/bucket, sigma~128 -> +32 sigma
#define SCAP 24576     // CAP + 512*8 alignment padding for sorted array

__device__ __forceinline__ void fatomic(float* p, float v) { unsafeAtomicAdd(p, v); }

// ---- phase 1: LDS-staged radix bucketing by dst>>9; packed = (src<<9)|(dst&511)
__global__ __launch_bounds__(256) void bucket_kernel(const int* __restrict__ ei,
                                                     unsigned* __restrict__ bcur,
                                                     unsigned* __restrict__ bedge) {
    int g = blockIdx.y;
    const int4* src4 = (const int4*)(ei + (size_t)g * 2 * E_);
    const int4* dst4 = (const int4*)(ei + (size_t)g * 2 * E_ + E_);
    unsigned* bc = bcur + (size_t)g * NB;
    unsigned* be = bedge + (size_t)g * NB * CAP;
    __shared__ unsigned hist[NB], curs[NB];
    int tid = threadIdx.x;
    const int CHUNK = 4096;
    const int nchunk = (E_ + CHUNK - 1) / CHUNK;
    for (int c = blockIdx.x; c < nchunk; c += gridDim.x) {
        int cb = c * CHUNK;
        for (int i = tid; i < NB; i += 256) hist[i] = 0u;
        __syncthreads();
        int4 sv[4], dv[4]; bool val[4];
#pragma unroll
        for (int k = 0; k < 4; ++k) {
            int e0 = cb + k * 1024 + tid * 4;
            val[k] = (e0 < E_);
            if (val[k]) { sv[k] = src4[e0 >> 2]; dv[k] = dst4[e0 >> 2]; }
        }
#pragma unroll
        for (int k = 0; k < 4; ++k) if (val[k]) {
            atomicAdd(&hist[((unsigned)dv[k].x) >> BSH], 1u);
            atomicAdd(&hist[((unsigned)dv[k].y) >> BSH], 1u);
            atomicAdd(&hist[((unsigned)dv[k].z) >> BSH], 1u);
            atomicAdd(&hist[((unsigned)dv[k].w) >> BSH], 1u);
        }
        __syncthreads();
        for (int i = tid; i < NB; i += 256) curs[i] = atomicAdd(&bc[i], hist[i]);
        __syncthreads();
#define EMIT(S, D) { unsigned bb = ((unsigned)(D)) >> BSH; \
        unsigned pos = atomicAdd(&curs[bb], 1u); \
        if (pos < CAP) be[(size_t)bb * CAP + pos] = (((unsigned)(S)) << BSH) | (((unsigned)(D)) & (BNODES - 1)); }
#pragma unroll
        for (int k = 0; k < 4; ++k) if (val[k]) {
            EMIT(sv[k].x, dv[k].x)
            EMIT(sv[k].y, dv[k].y)
            EMIT(sv[k].z, dv[k].z)
            EMIT(sv[k].w, dv[k].w)
        }
#undef EMIT
        __syncthreads();
    }
}

// ---- phase 1.5: per-bucket counting sort: hist -> dis + 8-aligned scan -> scatter
__global__ __launch_bounds__(256) void sortb_kernel(const unsigned* __restrict__ bcur,
                                                    const unsigned* __restrict__ bedge,
                                                    unsigned* __restrict__ ssrc,
                                                    unsigned* __restrict__ offA,
                                                    unsigned* __restrict__ degA,
                                                    float* __restrict__ dis) {
    int g = blockIdx.y, b = blockIdx.x;
    __shared__ unsigned hist[BNODES], offL[BNODES], curL[BNODES], part[256];
    int tid = threadIdx.x;
    hist[tid] = 0u; hist[tid + 256] = 0u;
    __syncthreads();
    unsigned n = bcur[(size_t)g * NB + b]; if (n > CAP) n = CAP;
    const unsigned* beb = bedge + ((size_t)g * NB + b) * CAP;
    for (unsigned i = tid; i < n; i += 256) atomicAdd(&hist[beb[i] & (BNODES - 1)], 1u);
    __syncthreads();
    unsigned d0 = hist[2 * tid], d1 = hist[2 * tid + 1];
    unsigned p0 = (d0 + 7u) & ~7u, p1 = (d1 + 7u) & ~7u;
    part[tid] = p0 + p1;
    __syncthreads();
    for (int o = 1; o < 256; o <<= 1) {
        unsigned v = (tid >= o) ? part[tid - o] : 0u;
        __syncthreads();
        part[tid] += v;
        __syncthreads();
    }
    unsigned base = part[tid] - p0 - p1;   // exclusive, multiple of 8
    offL[2 * tid] = base;     curL[2 * tid] = base;
    offL[2 * tid + 1] = base + p0; curL[2 * tid + 1] = base + p0;
    int node0 = b << BSH;
    unsigned sbase = (unsigned)(((size_t)g * NB + b) * SCAP);
    float* disg = dis + (size_t)g * N_;
    unsigned* offg = offA + (size_t)g * (NB << BSH);
    unsigned* degg = degA + (size_t)g * (NB << BSH);
    {
        int i = 2 * tid, node = node0 + i;
        offg[node] = sbase + offL[i]; degg[node] = d0;
        if (node < N_) disg[node] = rsqrtf((float)d0 + 1.0f);
        i = 2 * tid + 1; node = node0 + i;
        offg[node] = sbase + offL[i]; degg[node] = d1;
        if (node < N_) disg[node] = rsqrtf((float)d1 + 1.0f);
    }
    __syncthreads();
    for (unsigned i = tid; i < n; i += 256) {
        unsigned pk = beb[i];
        unsigned pos = atomicAdd(&curL[pk & (BNODES - 1)], 1u);
        ssrc[(size_t)sbase + pos] = pk >> BSH;
    }
}

// ---- hd = (x @ W1) * dis, stored split: [graph][half][N][8] -------------------
#define FMA4(acc, sv, wv) \
    acc.x += (sv) * (wv).x; acc.y += (sv) * (wv).y; acc.z += (sv) * (wv).z; acc.w += (sv) * (wv).w;

__global__ __launch_bounds__(256) void gemm_kernel(const float* __restrict__ x,
                                                   const float* __restrict__ W1,
                                                   const float* __restrict__ dis,
                                                   float* __restrict__ hd, int ntot) {
    __shared__ float wsh[DIM * HID];
    for (int i = threadIdx.x; i < DIM * HID; i += blockDim.x) wsh[i] = W1[i];
    __syncthreads();
    int node = blockIdx.x * blockDim.x + threadIdx.x;
    if (node >= ntot) return;
    const float4* xr = (const float4*)(x + (size_t)node * DIM);
    float4 a0 = {0,0,0,0}, a1 = {0,0,0,0}, a2 = {0,0,0,0}, a3 = {0,0,0,0};
    float4 q0, q1, q2, q3;
#define STEP(XS, B) \
    q0 = wr[(B)+0]; q1 = wr[(B)+1]; q2 = wr[(B)+2]; q3 = wr[(B)+3]; \
    FMA4(a0, XS, q0) FMA4(a1, XS, q1) FMA4(a2, XS, q2) FMA4(a3, XS, q3)
#pragma unroll 3
    for (int k4 = 0; k4 < DIM / 4; ++k4) {
        float4 xv = xr[k4];
        const float4* wr = (const float4*)(wsh + k4 * 4 * HID);
        STEP(xv.x, 0)
        STEP(xv.y, 4)
        STEP(xv.z, 8)
        STEP(xv.w, 12)
    }
#undef STEP
    float dn = dis[node];
    a0.x *= dn; a0.y *= dn; a0.z *= dn; a0.w *= dn;
    a1.x *= dn; a1.y *= dn; a1.z *= dn; a1.w *= dn;
    a2.x *= dn; a2.y *= dn; a2.z *= dn; a2.w *= dn;
    a3.x *= dn; a3.y *= dn; a3.z *= dn; a3.w *= dn;
    int gi = node / N_, local = node - gi * N_;
    float4* h0 = (float4*)(hd + (size_t)gi * N_ * HID + (size_t)local * 8);
    float4* h1 = (float4*)(hd + (size_t)gi * N_ * HID + (size_t)N_ * 8 + (size_t)local * 8);
    h0[0] = a0; h0[1] = a1;
    h1[0] = a2; h1[1] = a3;
}

// ---- phase 2: half-feature register aggregation -> t (h0 writes, h1 adds) -----
// 8 lanes/node; gathers 32 B/edge from a 3.2 MB per-graph half (L2-resident).
__global__ __launch_bounds__(512) void bagg_kernel(const unsigned* __restrict__ ssrc,
                                                   const unsigned* __restrict__ offA,
                                                   const unsigned* __restrict__ degA,
                                                   const float* __restrict__ hd,
                                                   const float* __restrict__ dis,
                                                   const float* __restrict__ b1,
                                                   const float* __restrict__ W2,
                                                   float* __restrict__ t_, int half) {
    int g = blockIdx.y, b = blockIdx.x;
    const float* hdh = hd + (size_t)g * N_ * HID + (size_t)half * N_ * 8;
    const float* disg = dis + (size_t)g * N_;
    const unsigned* offg = offA + (size_t)g * (NB << BSH);
    const unsigned* degg = degA + (size_t)g * (NB << BSH);
    float* tg = t_ + (size_t)g * N_;
    int tid = threadIdx.x, j = tid & 7, grp = tid >> 3;   // 64 node-groups
    float b1j = b1[half * 8 + j], w2j = W2[half * 8 + j];
    int node0 = b << BSH;
#pragma unroll 1
    for (int m = 0; m < 8; ++m) {
        int node = node0 + grp + (m << 6);
        if (node >= N_) continue;
        unsigned k0 = offg[node], dg = degg[node];
        float acc = hdh[(size_t)node * 8 + j];   // self-loop term
        unsigned k = 0;
        for (; k + 8 <= dg; k += 8) {
            const int4* ip = (const int4*)(ssrc + k0 + k);   // 16B-aligned
            int4 i0 = ip[0], i1 = ip[1];
            float v0 = hdh[(size_t)(unsigned)i0.x * 8 + j];
            float v1 = hdh[(size_t)(unsigned)i0.y * 8 + j];
            float v2 = hdh[(size_t)(unsigned)i0.z * 8 + j];
            float v3 = hdh[(size_t)(unsigned)i0.w * 8 + j];
            float v4 = hdh[(size_t)(unsigned)i1.x * 8 + j];
            float v5 = hdh[(size_t)(unsigned)i1.y * 8 + j];
            float v6 = hdh[(size_t)(unsigned)i1.z * 8 + j];
            float v7 = hdh[(size_t)(unsigned)i1.w * 8 + j];
            acc += ((v0 + v1) + (v2 + v3)) + ((v4 + v5) + (v6 + v7));
        }
        for (; k < dg; ++k) acc += hdh[(size_t)ssrc[k0 + k] * 8 + j];
        float dn = disg[node];
        float val = fmaxf(acc * dn + b1j, 0.f) * w2j;
        val += __shfl_xor(val, 1);
        val += __shfl_xor(val, 2);
        val += __shfl_xor(val, 4);
        if (j == 0) {
            float o = val * dn;
            if (half == 0) tg[node] = o;
            else tg[node] += o;
        }
    }
}

// ---- layer-2 via sorted lists: S[g] = sum_d dis[d]*(t[d] + sum_{s in in(d)} t[s])
__global__ __launch_bounds__(512) void score2_kernel(const unsigned* __restrict__ ssrc,
                                                     const unsigned* __restrict__ offA,
                                                     const unsigned* __restrict__ degA,
                                                     const float* __restrict__ t_,
                                                     const float* __restrict__ dis,
                                                     float* __restrict__ S) {
    int g = blockIdx.y, b = blockIdx.x;
    const float* tg = t_ + (size_t)g * N_;
    const float* disg = dis + (size_t)g * N_;
    const unsigned* offg = offA + (size_t)g * (NB << BSH);
    const unsigned* degg = degA + (size_t)g * (NB << BSH);
    int tid = threadIdx.x, j = tid & 3, grp = tid >> 2;   // 128 node-groups
    int node0 = b << BSH;
    float c = 0.f;
#pragma unroll 1
    for (int m = 0; m < 4; ++m) {
        int node = node0 + grp + (m << 7);
        if (node >= N_) continue;
        unsigned k0 = offg[node], dg = degg[node];
        float acc = 0.f;
        for (unsigned k = j; k < dg; k += 4) acc += tg[ssrc[k0 + k]];
        acc += __shfl_xor(acc, 1);
        acc += __shfl_xor(acc, 2);
        if (j == 0) c += disg[node] * (acc + tg[node]);
    }
    for (int o = 32; o > 0; o >>= 1) c += __shfl_down(c, o);
    __shared__ float red[8];
    int wid = tid >> 6, lane = tid & 63;
    if (lane == 0) red[wid] = c;
    __syncthreads();
    if (tid == 0) {
        float s = 0.f;
        for (int w = 0; w < 8; ++w) s += red[w];
        fatomic(&S[g], s);
    }
}

// ---- final: score = b2 + S/N, softmax over 5 ----------------------------------
__global__ void final_kernel(const float* __restrict__ S, const float* __restrict__ b2,
                             float* __restrict__ out) {
    if (threadIdx.x == 0) {
        float sc[NGRAPH];
        float m = -1e30f;
        for (int g = 0; g < NGRAPH; ++g) {
            sc[g] = b2[0] + S[g] * (1.0f / N_);
            m = fmaxf(m, sc[g]);
        }
        float sum = 0.f;
        for (int g = 0; g < NGRAPH; ++g) { sc[g] = expf(sc[g] - m); sum += sc[g]; }
        for (int g = 0; g < NGRAPH; ++g) out[g] = sc[g] / sum;
    }
}

extern "C" void kernel_launch(void* const* d_in, const int* in_sizes, int n_in,
                              void* d_out, int out_size, void* d_ws, size_t ws_size,
                              hipStream_t stream) {
    const float* emb = (const float*)d_in[0];
    const int* ei    = (const int*)d_in[1];   // int32 (validated R2)
    const float* W1  = (const float*)d_in[2];
    const float* b1  = (const float*)d_in[3];
    const float* W2  = (const float*)d_in[4];
    const float* b2  = (const float*)d_in[5];
    float* out = (float*)d_out;

    float* S = (float*)d_ws;
    unsigned* bcurAll = (unsigned*)((char*)d_ws + 256);
    size_t hdr = 256 + (size_t)NGRAPH * NB * 4;
    hdr = (hdr + 255) & ~(size_t)255;
    char* base = (char*)d_ws + hdr;
    size_t avail = (ws_size > hdr) ? ws_size - hdr : 0;

    size_t sz_be   = (size_t)NB * CAP * 4;      // ~16.1 MB
    size_t sz_ss   = (size_t)NB * SCAP * 4;     // ~19.3 MB
    size_t sz_off  = (size_t)(NB << BSH) * 4;   // ~0.4 MB
    size_t sz_hd   = (size_t)N_ * HID * 4;      // 6.4 MB
    size_t sz_dis  = (size_t)N_ * 4;
    size_t sz_t    = (size_t)N_ * 4;
    size_t per = sz_be + sz_ss + 2 * sz_off + sz_hd + sz_dis + sz_t + 1024;  // ~43.4 MB
    int maxChunk = (int)(avail / per);
    if (maxChunk > NGRAPH) maxChunk = NGRAPH;
    if (maxChunk < 1) maxChunk = 1;

    hipMemsetAsync(d_ws, 0, 256 + (size_t)NGRAPH * NB * 4, stream);

    for (int g0 = 0; g0 < NGRAPH; g0 += maxChunk) {
        int ng = (NGRAPH - g0 < maxChunk) ? (NGRAPH - g0) : maxChunk;
        char* p = base;
        unsigned* bedge = (unsigned*)p; p += (size_t)ng * sz_be;
        unsigned* ssrc  = (unsigned*)p; p += (size_t)ng * sz_ss;
        unsigned* offA  = (unsigned*)p; p += (size_t)ng * sz_off;
        unsigned* degA  = (unsigned*)p; p += (size_t)ng * sz_off;
        float* hd  = (float*)p; p += (size_t)ng * sz_hd;
        float* dis = (float*)p; p += (size_t)ng * sz_dis;
        float* t_  = (float*)p;
        unsigned* bcur = bcurAll + (size_t)g0 * NB;

        const int* eic  = ei  + (size_t)g0 * 2 * E_;
        const float* xc = emb + (size_t)g0 * N_ * DIM;

        bucket_kernel<<<dim3(128, ng), 256, 0, stream>>>(eic, bcur, bedge);
        sortb_kernel<<<dim3(NB, ng), 256, 0, stream>>>(bcur, bedge, ssrc, offA, degA, dis);
        gemm_kernel<<<dim3((ng * N_ + 255) / 256), 256, 0, stream>>>(xc, W1, dis, hd, ng * N_);
        bagg_kernel<<<dim3(NB, ng), 512, 0, stream>>>(ssrc, offA, degA, hd, dis, b1, W2, t_, 0);
        bagg_kernel<<<dim3(NB, ng), 512, 0, stream>>>(ssrc, offA, degA, hd, dis, b1, W2, t_, 1);
        score2_kernel<<<dim3(NB, ng), 512, 0, stream>>>(ssrc, offA, degA, t_, dis, S + g0);
    }
    final_kernel<<<1, 64, 0, stream>>>(S, b2, out);
}

// Round 9
// 884.336 us; speedup vs baseline: 1.2309x; 1.2309x over previous
//
#include <hip/hip_runtime.h>
#include <hip/hip_bf16.h>

#define N_ 100000
#define E_ 3200000
#define DIM 300
#define HID 16
#define NGRAPH 5
#define NB 196         // buckets/graph, 512 nodes each (196*512 >= 100000)
#define BSH 9
#define BNODES 512
#define CAP 20480      // mean 16384 edges/bucket, sigma~128 -> +32 sigma
#define SCAP 24576     // CAP + 512*8 alignment padding for sorted array

__device__ __forceinline__ void fatomic(float* p, float v) { unsafeAtomicAdd(p, v); }

// ---- phase 1: LDS-staged radix bucketing by dst>>9; packed = (src<<9)|(dst&511)
__global__ __launch_bounds__(256) void bucket_kernel(const int* __restrict__ ei,
                                                     unsigned* __restrict__ bcur,
                                                     unsigned* __restrict__ bedge) {
    int g = blockIdx.y;
    const int4* src4 = (const int4*)(ei + (size_t)g * 2 * E_);
    const int4* dst4 = (const int4*)(ei + (size_t)g * 2 * E_ + E_);
    unsigned* bc = bcur + (size_t)g * NB;
    unsigned* be = bedge + (size_t)g * NB * CAP;
    __shared__ unsigned hist[NB], curs[NB];
    int tid = threadIdx.x;
    const int CHUNK = 4096;
    const int nchunk = (E_ + CHUNK - 1) / CHUNK;
    for (int c = blockIdx.x; c < nchunk; c += gridDim.x) {
        int cb = c * CHUNK;
        for (int i = tid; i < NB; i += 256) hist[i] = 0u;
        __syncthreads();
        int4 sv[4], dv[4]; bool val[4];
#pragma unroll
        for (int k = 0; k < 4; ++k) {
            int e0 = cb + k * 1024 + tid * 4;
            val[k] = (e0 < E_);
            if (val[k]) { sv[k] = src4[e0 >> 2]; dv[k] = dst4[e0 >> 2]; }
        }
#pragma unroll
        for (int k = 0; k < 4; ++k) if (val[k]) {
            atomicAdd(&hist[((unsigned)dv[k].x) >> BSH], 1u);
            atomicAdd(&hist[((unsigned)dv[k].y) >> BSH], 1u);
            atomicAdd(&hist[((unsigned)dv[k].z) >> BSH], 1u);
            atomicAdd(&hist[((unsigned)dv[k].w) >> BSH], 1u);
        }
        __syncthreads();
        for (int i = tid; i < NB; i += 256) curs[i] = atomicAdd(&bc[i], hist[i]);
        __syncthreads();
#define EMIT(S, D) { unsigned bb = ((unsigned)(D)) >> BSH; \
        unsigned pos = atomicAdd(&curs[bb], 1u); \
        if (pos < CAP) be[(size_t)bb * CAP + pos] = (((unsigned)(S)) << BSH) | (((unsigned)(D)) & (BNODES - 1)); }
#pragma unroll
        for (int k = 0; k < 4; ++k) if (val[k]) {
            EMIT(sv[k].x, dv[k].x)
            EMIT(sv[k].y, dv[k].y)
            EMIT(sv[k].z, dv[k].z)
            EMIT(sv[k].w, dv[k].w)
        }
#undef EMIT
        __syncthreads();
    }
}

// ---- phase 1.5: per-bucket counting sort: hist -> dis + 8-aligned scan -> scatter
__global__ __launch_bounds__(256) void sortb_kernel(const unsigned* __restrict__ bcur,
                                                    const unsigned* __restrict__ bedge,
                                                    unsigned* __restrict__ ssrc,
                                                    unsigned* __restrict__ offA,
                                                    unsigned* __restrict__ degA,
                                                    float* __restrict__ dis) {
    int g = blockIdx.y, b = blockIdx.x;
    __shared__ unsigned hist[BNODES], offL[BNODES], curL[BNODES], part[256];
    int tid = threadIdx.x;
    hist[tid] = 0u; hist[tid + 256] = 0u;
    __syncthreads();
    unsigned n = bcur[(size_t)g * NB + b]; if (n > CAP) n = CAP;
    const unsigned* beb = bedge + ((size_t)g * NB + b) * CAP;
    for (unsigned i = tid; i < n; i += 256) atomicAdd(&hist[beb[i] & (BNODES - 1)], 1u);
    __syncthreads();
    unsigned d0 = hist[2 * tid], d1 = hist[2 * tid + 1];
    unsigned p0 = (d0 + 7u) & ~7u, p1 = (d1 + 7u) & ~7u;
    part[tid] = p0 + p1;
    __syncthreads();
    for (int o = 1; o < 256; o <<= 1) {
        unsigned v = (tid >= o) ? part[tid - o] : 0u;
        __syncthreads();
        part[tid] += v;
        __syncthreads();
    }
    unsigned base = part[tid] - p0 - p1;   // exclusive, multiple of 8
    offL[2 * tid] = base;     curL[2 * tid] = base;
    offL[2 * tid + 1] = base + p0; curL[2 * tid + 1] = base + p0;
    int node0 = b << BSH;
    unsigned sbase = (unsigned)(((size_t)g * NB + b) * SCAP);
    float* disg = dis + (size_t)g * N_;
    unsigned* offg = offA + (size_t)g * (NB << BSH);
    unsigned* degg = degA + (size_t)g * (NB << BSH);
    {
        int i = 2 * tid, node = node0 + i;
        offg[node] = sbase + offL[i]; degg[node] = d0;
        if (node < N_) disg[node] = rsqrtf((float)d0 + 1.0f);
        i = 2 * tid + 1; node = node0 + i;
        offg[node] = sbase + offL[i]; degg[node] = d1;
        if (node < N_) disg[node] = rsqrtf((float)d1 + 1.0f);
    }
    __syncthreads();
    for (unsigned i = tid; i < n; i += 256) {
        unsigned pk = beb[i];
        unsigned pos = atomicAdd(&curL[pk & (BNODES - 1)], 1u);
        ssrc[(size_t)sbase + pos] = pk >> BSH;
    }
}

// ---- hd = (x @ W1) * dis[node]  (thread-per-node, W1 in LDS) ------------------
#define FMA4(acc, sv, wv) \
    acc.x += (sv) * (wv).x; acc.y += (sv) * (wv).y; acc.z += (sv) * (wv).z; acc.w += (sv) * (wv).w;

__global__ __launch_bounds__(256) void gemm_kernel(const float* __restrict__ x,
                                                   const float* __restrict__ W1,
                                                   const float* __restrict__ dis,
                                                   float* __restrict__ hd, int ntot) {
    __shared__ float wsh[DIM * HID];
    for (int i = threadIdx.x; i < DIM * HID; i += blockDim.x) wsh[i] = W1[i];
    __syncthreads();
    int node = blockIdx.x * blockDim.x + threadIdx.x;
    if (node >= ntot) return;
    const float4* xr = (const float4*)(x + (size_t)node * DIM);
    float4 a0 = {0,0,0,0}, a1 = {0,0,0,0}, a2 = {0,0,0,0}, a3 = {0,0,0,0};
    float4 q0, q1, q2, q3;
#define STEP(XS, B) \
    q0 = wr[(B)+0]; q1 = wr[(B)+1]; q2 = wr[(B)+2]; q3 = wr[(B)+3]; \
    FMA4(a0, XS, q0) FMA4(a1, XS, q1) FMA4(a2, XS, q2) FMA4(a3, XS, q3)
#pragma unroll 3
    for (int k4 = 0; k4 < DIM / 4; ++k4) {
        float4 xv = xr[k4];
        const float4* wr = (const float4*)(wsh + k4 * 4 * HID);
        STEP(xv.x, 0)
        STEP(xv.y, 4)
        STEP(xv.z, 8)
        STEP(xv.w, 12)
    }
#undef STEP
    float dn = dis[node];
    a0.x *= dn; a0.y *= dn; a0.z *= dn; a0.w *= dn;
    a1.x *= dn; a1.y *= dn; a1.z *= dn; a1.w *= dn;
    a2.x *= dn; a2.y *= dn; a2.z *= dn; a2.w *= dn;
    a3.x *= dn; a3.y *= dn; a3.z *= dn; a3.w *= dn;
    float4* hr = (float4*)(hd + (size_t)node * HID);
    hr[0] = a0; hr[1] = a1; hr[2] = a2; hr[3] = a3;
}

// ---- phase 2: per-node register aggregation + fused epilogue -> t[node] -------
// 16 lanes/node (lane = feature). ZERO atomics, ZERO LDS, no barriers.
// 8-deep gather pipeline; index loads are 2x uniform int4 (8-aligned offsets).
__global__ __launch_bounds__(512) void bagg_kernel(const unsigned* __restrict__ ssrc,
                                                   const unsigned* __restrict__ offA,
                                                   const unsigned* __restrict__ degA,
                                                   const float* __restrict__ hd,
                                                   const float* __restrict__ dis,
                                                   const float* __restrict__ b1,
                                                   const float* __restrict__ W2,
                                                   float* __restrict__ t_) {
    int g = blockIdx.y, b = blockIdx.x;
    const float* hdg = hd + (size_t)g * N_ * HID;
    const float* disg = dis + (size_t)g * N_;
    const unsigned* offg = offA + (size_t)g * (NB << BSH);
    const unsigned* degg = degA + (size_t)g * (NB << BSH);
    float* tg = t_ + (size_t)g * N_;
    int tid = threadIdx.x, j = tid & 15, sub = tid >> 4;   // 32 node-groups
    float b1j = b1[j], w2j = W2[j];
    int node0 = b << BSH;
#pragma unroll 1
    for (int m = 0; m < 16; ++m) {
        int node = node0 + sub + (m << 5);
        if (node >= N_) continue;
        unsigned k0 = offg[node], dg = degg[node];
        float acc = hdg[(size_t)node * HID + j];   // self-loop term
        unsigned k = 0;
        for (; k + 8 <= dg; k += 8) {
            const int4* ip = (const int4*)(ssrc + k0 + k);   // 16B-aligned (k0%8==0)
            int4 i0 = ip[0], i1 = ip[1];
            float v0 = hdg[(size_t)(unsigned)i0.x * HID + j];
            float v1 = hdg[(size_t)(unsigned)i0.y * HID + j];
            float v2 = hdg[(size_t)(unsigned)i0.z * HID + j];
            float v3 = hdg[(size_t)(unsigned)i0.w * HID + j];
            float v4 = hdg[(size_t)(unsigned)i1.x * HID + j];
            float v5 = hdg[(size_t)(unsigned)i1.y * HID + j];
            float v6 = hdg[(size_t)(unsigned)i1.z * HID + j];
            float v7 = hdg[(size_t)(unsigned)i1.w * HID + j];
            acc += ((v0 + v1) + (v2 + v3)) + ((v4 + v5) + (v6 + v7));
        }
        for (; k < dg; ++k) acc += hdg[(size_t)ssrc[k0 + k] * HID + j];
        float dn = disg[node];
        float val = fmaxf(acc * dn + b1j, 0.f) * w2j;
        val += __shfl_xor(val, 1);
        val += __shfl_xor(val, 2);
        val += __shfl_xor(val, 4);
        val += __shfl_xor(val, 8);
        if (j == 0) tg[node] = val * dn;
    }
}

// ---- layer-2 via sorted lists: S[g] = sum_d dis[d]*(t[d] + sum_{s in in(d)} t[s])
__global__ __launch_bounds__(512) void score2_kernel(const unsigned* __restrict__ ssrc,
                                                     const unsigned* __restrict__ offA,
                                                     const unsigned* __restrict__ degA,
                                                     const float* __restrict__ t_,
                                                     const float* __restrict__ dis,
                                                     float* __restrict__ S) {
    int g = blockIdx.y, b = blockIdx.x;
    const float* tg = t_ + (size_t)g * N_;
    const float* disg = dis + (size_t)g * N_;
    const unsigned* offg = offA + (size_t)g * (NB << BSH);
    const unsigned* degg = degA + (size_t)g * (NB << BSH);
    int tid = threadIdx.x, j = tid & 3, grp = tid >> 2;   // 128 node-groups
    int node0 = b << BSH;
    float c = 0.f;
#pragma unroll 1
    for (int m = 0; m < 4; ++m) {
        int node = node0 + grp + (m << 7);
        if (node >= N_) continue;
        unsigned k0 = offg[node], dg = degg[node];
        float acc = 0.f;
        for (unsigned k = j; k < dg; k += 4) acc += tg[ssrc[k0 + k]];
        acc += __shfl_xor(acc, 1);
        acc += __shfl_xor(acc, 2);
        if (j == 0) c += disg[node] * (acc + tg[node]);
    }
    for (int o = 32; o > 0; o >>= 1) c += __shfl_down(c, o);
    __shared__ float red[8];
    int wid = tid >> 6, lane = tid & 63;
    if (lane == 0) red[wid] = c;
    __syncthreads();
    if (tid == 0) {
        float s = 0.f;
        for (int w = 0; w < 8; ++w) s += red[w];
        fatomic(&S[g], s);
    }
}

// ---- final: score = b2 + S/N, softmax over 5 ----------------------------------
__global__ void final_kernel(const float* __restrict__ S, const float* __restrict__ b2,
                             float* __restrict__ out) {
    if (threadIdx.x == 0) {
        float sc[NGRAPH];
        float m = -1e30f;
        for (int g = 0; g < NGRAPH; ++g) {
            sc[g] = b2[0] + S[g] * (1.0f / N_);
            m = fmaxf(m, sc[g]);
        }
        float sum = 0.f;
        for (int g = 0; g < NGRAPH; ++g) { sc[g] = expf(sc[g] - m); sum += sc[g]; }
        for (int g = 0; g < NGRAPH; ++g) out[g] = sc[g] / sum;
    }
}

extern "C" void kernel_launch(void* const* d_in, const int* in_sizes, int n_in,
                              void* d_out, int out_size, void* d_ws, size_t ws_size,
                              hipStream_t stream) {
    const float* emb = (const float*)d_in[0];
    const int* ei    = (const int*)d_in[1];   // int32 (validated R2)
    const float* W1  = (const float*)d_in[2];
    const float* b1  = (const float*)d_in[3];
    const float* W2  = (const float*)d_in[4];
    const float* b2  = (const float*)d_in[5];
    float* out = (float*)d_out;

    float* S = (float*)d_ws;
    unsigned* bcurAll = (unsigned*)((char*)d_ws + 256);
    size_t hdr = 256 + (size_t)NGRAPH * NB * 4;
    hdr = (hdr + 255) & ~(size_t)255;
    char* base = (char*)d_ws + hdr;
    size_t avail = (ws_size > hdr) ? ws_size - hdr : 0;

    size_t sz_be   = (size_t)NB * CAP * 4;      // ~16.1 MB
    size_t sz_ss   = (size_t)NB * SCAP * 4;     // ~19.3 MB
    size_t sz_off  = (size_t)(NB << BSH) * 4;   // ~0.4 MB
    size_t sz_hd   = (size_t)N_ * HID * 4;      // 6.4 MB
    size_t sz_dis  = (size_t)N_ * 4;
    size_t sz_t    = (size_t)N_ * 4;
    size_t per = sz_be + sz_ss + 2 * sz_off + sz_hd + sz_dis + sz_t + 1024;  // ~43.4 MB
    int maxChunk = (int)(avail / per);
    if (maxChunk > NGRAPH) maxChunk = NGRAPH;
    if (maxChunk < 1) maxChunk = 1;

    hipMemsetAsync(d_ws, 0, 256 + (size_t)NGRAPH * NB * 4, stream);

    for (int g0 = 0; g0 < NGRAPH; g0 += maxChunk) {
        int ng = (NGRAPH - g0 < maxChunk) ? (NGRAPH - g0) : maxChunk;
        char* p = base;
        unsigned* bedge = (unsigned*)p; p += (size_t)ng * sz_be;
        unsigned* ssrc  = (unsigned*)p; p += (size_t)ng * sz_ss;
        unsigned* offA  = (unsigned*)p; p += (size_t)ng * sz_off;
        unsigned* degA  = (unsigned*)p; p += (size_t)ng * sz_off;
        float* hd  = (float*)p; p += (size_t)ng * sz_hd;
        float* dis = (float*)p; p += (size_t)ng * sz_dis;
        float* t_  = (float*)p;
        unsigned* bcur = bcurAll + (size_t)g0 * NB;

        const int* eic  = ei  + (size_t)g0 * 2 * E_;
        const float* xc = emb + (size_t)g0 * N_ * DIM;

        bucket_kernel<<<dim3(128, ng), 256, 0, stream>>>(eic, bcur, bedge);
        sortb_kernel<<<dim3(NB, ng), 256, 0, stream>>>(bcur, bedge, ssrc, offA, degA, dis);
        gemm_kernel<<<dim3((ng * N_ + 255) / 256), 256, 0, stream>>>(xc, W1, dis, hd, ng * N_);
        bagg_kernel<<<dim3(NB, ng), 512, 0, stream>>>(ssrc, offA, degA, hd, dis, b1, W2, t_);
        score2_kernel<<<dim3(NB, ng), 512, 0, stream>>>(ssrc, offA, degA, t_, dis, S + g0);
    }
    final_kernel<<<1, 64, 0, stream>>>(S, b2, out);
}